// Round 5
// baseline (96.664 us; speedup 1.0000x reference)
//
#include <hip/hip_runtime.h>
#include <math.h>

#define OUT_H 7
#define OUT_W 7
#define NBINS (OUT_H * OUT_W)

// ---------------------------------------------------------------------------
// Kernel 1: transpose features (B,C,H,W) -> (B,H*W,C) into workspace.
// 64x64 tiles via LDS (pad 65 to kill bank conflicts), float4 on both global
// sides. Makes the pooling kernel's channel reads perfectly coalesced.
// ---------------------------------------------------------------------------
__global__ __launch_bounds__(256) void transpose_kernel(
    const float* __restrict__ in, float* __restrict__ out, int C, int P)
{
    __shared__ float tile[64][65];

    const int pt = blockIdx.x;   // p-tile (P/64)
    const int ct = blockIdx.y;   // c-tile (C/64)
    const int b  = blockIdx.z;

    const int p0 = pt * 64;
    const int c0 = ct * 64;

    const int pq = threadIdx.x & 15;   // p quad index (0..15) -> 4 floats
    const int cr = threadIdx.x >> 4;   // 0..15

    // Load: in[b][c0+c_local][p0 + pq*4 .. +3]
    #pragma unroll
    for (int k = 0; k < 4; ++k) {
        int c_local = cr + 16 * k;
        const float4 v = *(const float4*)&in[((size_t)(b * C + c0 + c_local)) * P + p0 + pq * 4];
        tile[c_local][pq * 4 + 0] = v.x;
        tile[c_local][pq * 4 + 1] = v.y;
        tile[c_local][pq * 4 + 2] = v.z;
        tile[c_local][pq * 4 + 3] = v.w;
    }
    __syncthreads();

    // Store: out[b][p0+p_local][c0 + pq*4 .. +3]
    #pragma unroll
    for (int k = 0; k < 4; ++k) {
        int p_local = cr + 16 * k;
        float4 w;
        w.x = tile[pq * 4 + 0][p_local];
        w.y = tile[pq * 4 + 1][p_local];
        w.z = tile[pq * 4 + 2][p_local];
        w.w = tile[pq * 4 + 3][p_local];
        *(float4*)&out[((size_t)(b * P + p0 + p_local)) * C + c0 + pq * 4] = w;
    }
}

// ---------------------------------------------------------------------------
// Kernel 2: one block per (roi, bin); thread = channel. Window bounds are
// block-uniform (no divergence); each (y,x) step reads 256 consecutive
// floats (coalesced 1KB). Bin bounds: exact integer floor(k*roi/7)=(k*roi)/7,
// matching the f64 numpy reference (validated round 4, absmax 0).
// ---------------------------------------------------------------------------
__global__ __launch_bounds__(256) void pool_kernel(
    const float* __restrict__ featT,   // (B, H*W, C) channel-last
    const int* __restrict__ rois,
    float* __restrict__ out, int C, int H, int W)
{
    const int bin = blockIdx.x % NBINS;
    const int n   = blockIdx.x / NBINS;
    const int c   = threadIdx.x;

    const int ph = bin / OUT_W;
    const int pw = bin % OUT_W;

    const int* r = rois + n * 5;
    const int b  = r[0];
    const int x1 = r[1];
    const int y1 = r[2];
    const int x2 = r[3];
    const int y2 = r[4];

    const int roi_h = y2 - y1 + 1;
    const int roi_w = x2 - x1 + 1;

    int hs = (ph * roi_h) / OUT_H;
    int he = ((ph + 1) * roi_h) / OUT_H;
    hs = hs < (roi_h - 1) ? hs : (roi_h - 1);
    he = he < roi_h ? he : roi_h;

    int ws = (pw * roi_w) / OUT_W;
    int we = ((pw + 1) * roi_w) / OUT_W;
    ws = ws < (roi_w - 1) ? ws : (roi_w - 1);
    we = we < roi_w ? we : roi_w;

    float result = 0.0f;
    if (he > hs && we > ws) {        // block-uniform branch
        float m = -INFINITY;
        const int y_lo = y1 + hs, y_hi = y1 + he;
        const int x_lo = x1 + ws, x_hi = x1 + we;
        for (int y = y_lo; y < y_hi; ++y) {
            const float* rowp = featT + (((size_t)b * (H * W) + (size_t)y * W + x_lo) * C) + c;
            for (int x = x_lo; x < x_hi; ++x) {
                m = fmaxf(m, *rowp);
                rowp += C;
            }
        }
        result = m;
    }
    // out[n][c][ph][pw]
    out[((size_t)(n * C + c)) * NBINS + bin] = result;
}

extern "C" void kernel_launch(void* const* d_in, const int* in_sizes, int n_in,
                              void* d_out, int out_size, void* d_ws, size_t ws_size,
                              hipStream_t stream) {
    const float* feat = (const float*)d_in[0];
    const int*   rois = (const int*)d_in[1];
    float*       out  = (float*)d_out;
    float*       featT = (float*)d_ws;    // 4*64*64*256*4B = 16 MB

    const int C = 256, H = 64, W = 64;
    const int P = H * W;                  // 4096
    const int B = 4;
    const int N = in_sizes[1] / 5;        // 128

    dim3 tgrid(P / 64, C / 64, B);        // 64 x 4 x 4 = 1024 blocks
    transpose_kernel<<<tgrid, 256, 0, stream>>>(feat, featT, C, P);

    pool_kernel<<<N * NBINS, 256, 0, stream>>>(featT, rois, out, C, H, W);
}